// Round 1
// baseline (601.201 us; speedup 1.0000x reference)
//
#include <hip/hip_runtime.h>

// ConvCapsuleLayer: 5x5 SAME conv (128 folded images, 16->256 ch) + 3x dynamic routing.
// Fused single kernel: block = one (b,h,w) output position, thread = output channel.

#define HH    32
#define WWID  32
#define INC   8
#define INA   16
#define KS    5
#define OUTC  8
#define OUTA  32
#define CHN   256   // OUTC*OUTA

__global__ __launch_bounds__(256) void capsconv_route_kernel(
    const float* __restrict__ inp,   // [16][32][32][8][16]
    const float* __restrict__ Wt,    // [5][5][16][256]
    const float* __restrict__ bias,  // [256]  (b flat: [c][a])
    float* __restrict__ out)         // [16][32][32][8][32]
{
  const int tid = threadIdx.x;          // ch = c*32 + a
  const int bid = blockIdx.x;
  const int w0 = bid & 31;
  const int h0 = (bid >> 5) & 31;
  const int bb = bid >> 10;             // output batch
  // TF reshape scramble: votes[bb][ii] = conv image n = bb*8+ii,
  // conv image n reads inputs[b_src = n%16][...][i_src = n/16][...]
  const int i_src = bb >> 1;
  const int b_base = (bb & 1) * 8;      // b_src = b_base + ii

  // ---- conv: 8 votes per thread (one per input capsule ii) ----
  float acc[8];
  #pragma unroll
  for (int i = 0; i < 8; ++i) acc[i] = 0.f;

  for (int kh = 0; kh < KS; ++kh) {
    const int hh = h0 + kh - 2;
    if (hh < 0 || hh >= HH) continue;
    for (int kw = 0; kw < KS; ++kw) {
      const int ww = w0 + kw - 2;
      if (ww < 0 || ww >= WWID) continue;
      // W slice for this (kh,kw): 16 coalesced vector loads (stride 256 floats)
      const float* wp = Wt + (size_t)((kh * KS + kw) * INA) * CHN + tid;
      float wreg[INA];
      #pragma unroll
      for (int ia = 0; ia < INA; ++ia) wreg[ia] = wp[(size_t)ia * CHN];
      #pragma unroll
      for (int i = 0; i < 8; ++i) {
        // block-uniform address -> scalar loads (SGPR broadcast into v_fmac)
        const float* xp = inp + ((((size_t)(b_base + i) * HH + hh) * WWID + ww) * INC + i_src) * INA;
        #pragma unroll
        for (int ia = 0; ia < INA; ++ia)
          acc[i] = fmaf(xp[ia], wreg[ia], acc[i]);
      }
    }
  }

  // ---- dynamic routing (3 iterations), all in registers + shfl ----
  const int c = tid >> 5;               // output capsule of this thread
  const float bv = bias[tid];
  float logit[8];
  #pragma unroll
  for (int i = 0; i < 8; ++i) logit[i] = 0.f;

  __shared__ float lds_logit[8][8];     // [ii][c]

  float act = 0.f;
  for (int r = 0; r < 3; ++r) {
    float preact = bv;
    if (r == 0) {
      // softmax(zeros) = 1/8 uniformly
      float s = 0.f;
      #pragma unroll
      for (int i = 0; i < 8; ++i) s += acc[i];
      preact = fmaf(0.125f, s, preact);
    } else {
      if ((tid & 31) == 0) {
        #pragma unroll
        for (int i = 0; i < 8; ++i) lds_logit[i][c] = logit[i];
      }
      __syncthreads();
      #pragma unroll
      for (int i = 0; i < 8; ++i) {
        float l[8];
        #pragma unroll
        for (int cc = 0; cc < 8; ++cc) l[cc] = lds_logit[i][cc];
        float mx = fmaxf(fmaxf(fmaxf(l[0], l[1]), fmaxf(l[2], l[3])),
                         fmaxf(fmaxf(l[4], l[5]), fmaxf(l[6], l[7])));
        float den = 0.f;
        #pragma unroll
        for (int cc = 0; cc < 8; ++cc) den += __expf(l[cc] - mx);
        float route = __expf(logit[i] - mx) / den;
        preact = fmaf(route, acc[i], preact);
      }
      __syncthreads();   // protect LDS before next iteration's writes
    }
    // squash over the 32 atom lanes (a = tid&31; groups never cross the 32-lane boundary)
    float nsq = preact * preact;
    #pragma unroll
    for (int m = 16; m >= 1; m >>= 1) nsq += __shfl_xor(nsq, m, 64);
    float norm = sqrtf(nsq);
    act = preact * (norm / (1.f + nsq));

    if (r < 2) {
      #pragma unroll
      for (int i = 0; i < 8; ++i) {
        float d = acc[i] * act;
        #pragma unroll
        for (int m = 16; m >= 1; m >>= 1) d += __shfl_xor(d, m, 64);
        logit[i] += d;
      }
    }
  }

  // out[bb][h0][w0][c][a] : bid*256 + tid (coalesced)
  out[(size_t)bid * CHN + tid] = act;
}

extern "C" void kernel_launch(void* const* d_in, const int* in_sizes, int n_in,
                              void* d_out, int out_size, void* d_ws, size_t ws_size,
                              hipStream_t stream) {
  (void)in_sizes; (void)n_in; (void)d_ws; (void)ws_size; (void)out_size;
  const float* inp  = (const float*)d_in[0];
  const float* Wt   = (const float*)d_in[1];
  const float* bv   = (const float*)d_in[2];
  float* out        = (float*)d_out;
  dim3 grid(16 * 32 * 32);   // (b,h,w)
  dim3 block(256);
  hipLaunchKernelGGL(capsconv_route_kernel, grid, block, 0, stream, inp, Wt, bv, out);
}